// Round 9
// baseline (206.180 us; speedup 1.0000x reference)
//
#include <hip/hip_runtime.h>

// GCN layer: out = (D^-1/2 (A+I) D^-1/2) X W^T + b
// N=100000, E=1600000, D=64.
//
// Round 20: scatter is LATENCY-bound, not BW-bound. r19 counters: WRITE
// dropped 51->17MB as designed yet dur stayed 44us at hbm 520GB/s (6%),
// VALUBusy 3%, Occupancy 13% -- stores are fire-and-forget; the time is
// serial global-load latency (runtime-bound loops defeat load batching:
// ~16 x 900cyc per pass) with only 2 blocks/CU (62KB LDS) to hide it.
// Fix, scatter only:
//   1. EPB 2048 -> 782 blocks (3/CU co-resident);
//   2. drop lrec/lbk staging (pass 3 re-reads ei, L2-hot) -> LDS 24.6KB
//      -> 6 blocks/CU allowed;
//   3. fixed-trip unrolled guarded passes (8 iters) -> 8 loads in flight
//      per pass instead of 1.
// Counting-sort write kept (keeps writes off the ~1TB/s scattered-store
// ceiling at zero cost). gemm_scaled + csr_gather byte-identical to r18.
//
// Pipeline: D0 memset gcur | D1 scatter | D2 gemm_scaled | D3 csr_gather

#define BSHIFT 7
#define BNODES 128
#define CAP 3072   // records per bucket region (mean 2046, P(overflow)~1e-90)
#define EPB 2048   // edges per scatter block -> 782 blocks
#define SPASS (EPB / 256)  // unrolled iterations per scatter pass

typedef short bf16x8 __attribute__((ext_vector_type(8)));
typedef float f32x4 __attribute__((ext_vector_type(4)));

__device__ inline unsigned short f2b_rn(float f) {
    unsigned u = __float_as_uint(f);
    unsigned r = u + 0x7FFFu + ((u >> 16) & 1u);
    return (unsigned short)(r >> 16);
}
__device__ inline float b2f(unsigned short h) {
    return __uint_as_float(((unsigned)h) << 16);
}

// split 8 fp32 (two float4) into hi (truncated bf16) + lo (bf16 of residual)
__device__ inline void split8(float4 a, float4 b, bf16x8* hi, bf16x8* lo) {
    float f[8] = {a.x, a.y, a.z, a.w, b.x, b.y, b.z, b.w};
    union U { unsigned u[4]; bf16x8 v; } uh, ul;
#pragma unroll
    for (int i = 0; i < 4; ++i) {
        unsigned u0 = __float_as_uint(f[2 * i]);
        unsigned u1 = __float_as_uint(f[2 * i + 1]);
        uh.u[i] = (u0 >> 16) | (u1 & 0xFFFF0000u);
        float r0 = f[2 * i]     - __uint_as_float(u0 & 0xFFFF0000u);
        float r1 = f[2 * i + 1] - __uint_as_float(u1 & 0xFFFF0000u);
        unsigned v0 = __float_as_uint(r0);
        unsigned v1 = __float_as_uint(r1);
        ul.u[i] = (v0 >> 16) | (v1 & 0xFFFF0000u);
    }
    *hi = uh.v;
    *lo = ul.v;
}

// --- D1: binned scatter; slim LDS, unrolled passes, counting-sort write ---
__global__ __launch_bounds__(256) void scatter_kernel(
    const int* __restrict__ ei, int* __restrict__ gcur,
    unsigned int* __restrict__ grec, int e, int nbuck) {
    __shared__ unsigned int lsort[EPB];      //  8192 B: records sorted by bucket
    __shared__ unsigned short sbk[EPB];      //  4096 B: bucket of sorted slot
    __shared__ int lh[1024];                 //  4096 B: hist, then cursor
    __shared__ int lscan[1024];              //  4096 B: exclusive offsets
    __shared__ int gbase[1024];              //  4096 B: global base per bucket
    __shared__ int wsum[4];
    int t = threadIdx.x;
    for (int i = t; i < nbuck; i += 256) lh[i] = 0;
    __syncthreads();

    int e0 = blockIdx.x * EPB;
    int m = e - e0;
    if (m > EPB) m = EPB;

    // pass 1: histogram dst buckets (8 independent loads in flight)
#pragma unroll
    for (int j = 0; j < SPASS; ++j) {
        int i = t + j * 256;
        if (i < m) atomicAdd(&lh[ei[e + e0 + i] >> BSHIFT], 1);
    }
    __syncthreads();

    // pass 2: exclusive scan over nbuck bins (4 bins/thread + shfl scan)
    int b0 = t << 2;
    int c[4], v4[4], ssum = 0;
#pragma unroll
    for (int j = 0; j < 4; ++j) {
        int bb = b0 + j;
        int v = (bb < nbuck) ? lh[bb] : 0;
        c[j] = ssum;
        v4[j] = v;
        ssum += v;
    }
    int lane = t & 63, w = t >> 6;
    int vi = ssum;
#pragma unroll
    for (int o = 1; o < 64; o <<= 1) {
        int u = __shfl_up(vi, o, 64);
        if (lane >= o) vi += u;
    }
    if (lane == 63) wsum[w] = vi;
    __syncthreads();   // wsum ready; all lh reads done
    int woff = 0;
#pragma unroll
    for (int j = 0; j < 4; ++j)
        if (j < w) woff += wsum[j];
    int ex = woff + vi - ssum;  // exclusive prefix for this thread's bins
#pragma unroll
    for (int j = 0; j < 4; ++j) {
        int bb = b0 + j;
        if (bb < nbuck) {
            lscan[bb] = ex + c[j];
            gbase[bb] = v4[j] ? atomicAdd(&gcur[bb], v4[j]) : 0;
            lh[bb] = 0;  // cursor for pass 3
        }
    }
    __syncthreads();

    // pass 3: LDS counting sort (re-read ei; dst row L2-hot)
#pragma unroll
    for (int j = 0; j < SPASS; ++j) {
        int i = t + j * 256;
        if (i < m) {
            int g = e0 + i;
            int s = ei[g];
            int d = ei[e + g];
            int b = d >> BSHIFT;
            int sp = lscan[b] + atomicAdd(&lh[b], 1);
            lsort[sp] = ((unsigned int)s << BSHIFT) | (unsigned int)(d & (BNODES - 1));
            sbk[sp] = (unsigned short)b;
        }
    }
    __syncthreads();

    // pass 4: sorted write -- consecutive lanes, mostly-consecutive addrs
#pragma unroll
    for (int j = 0; j < SPASS; ++j) {
        int i = t + j * 256;
        if (i < m) {
            int b = sbk[i];
            int pos = gbase[b] + (i - lscan[b]);
            if (pos < CAP)
                grec[(size_t)b * CAP + pos] = lsort[i];
        }
    }
}

// --- D2: bucket-aligned MFMA gemm + deg hist + pre-scaled bf16 out ---
// Block b = bucket b = nodes [128b, 128b+128); 512 thr = 8 waves x 16 nodes.
__global__ __launch_bounds__(512) void gemm_scaled_kernel(
    const float* __restrict__ x, const float* __restrict__ W,
    ushort4* __restrict__ yh,
    const unsigned int* __restrict__ grec, const int* __restrict__ gcur,
    int n) {
    __shared__ bf16x8 Whi[512];   // 8KB: pre-split W fragments, frag f =
    __shared__ bf16x8 Wlo[512];   // 8KB: ((tt*2+kb)*4+g)*16+jn  (= lane order)
    __shared__ int lh[BNODES];
    int t = threadIdx.x;
    int b = blockIdx.x;
    int node0 = b << BSHIFT;

    if (t < BNODES) lh[t] = 0;
    __syncthreads();

    // deg hist over this bucket's grec region (~2K records, L2/L3-hot)
    size_t base = (size_t)b * CAP;
    int cnt = gcur[b];
    if (cnt > CAP) cnt = CAP;
    for (int i = t; i < cnt; i += 512)
        atomicAdd(&lh[grec[base + i] & (BNODES - 1)], 1);

    // stage split-bf16 W fragments (once per block; 16KB L2-hot reads)
    {
        int tt = t >> 7, kb = (t >> 6) & 1, g = (t >> 4) & 3, jn = t & 15;
        const float4* wp =
            (const float4*)(W + (size_t)(tt * 16 + jn) * 64 + kb * 32 + g * 8);
        bf16x8 hi, lo;
        split8(wp[0], wp[1], &hi, &lo);
        Whi[t] = hi;
        Wlo[t] = lo;
    }
    __syncthreads();

    int wave = t >> 6, lane = t & 63;
    int jn = lane & 15;      // node within wave tile (B-frag / D col)
    int g = lane >> 4;       // k-subgroup: elements k = 8g..8g+7 (+32*kb)
    int node = node0 + wave * 16 + jn;

    // x fragments: hi/lo for kb=0,1
    bf16x8 xhi[2], xlo[2];
#pragma unroll
    for (int kb = 0; kb < 2; ++kb) {
        float4 p0 = {0.f, 0.f, 0.f, 0.f}, p1 = {0.f, 0.f, 0.f, 0.f};
        if (node < n) {
            const float4* xp =
                (const float4*)(x + (size_t)node * 64 + kb * 32 + g * 8);
            p0 = xp[0];
            p1 = xp[1];
        }
        split8(p0, p1, &xhi[kb], &xlo[kb]);
    }

    float dn = rsqrtf((float)lh[wave * 16 + jn] + 1.0f);  // +1 self loop

#pragma unroll
    for (int tt = 0; tt < 4; ++tt) {
        f32x4 acc = {0.f, 0.f, 0.f, 0.f};
#pragma unroll
        for (int kb = 0; kb < 2; ++kb) {
            bf16x8 whi = Whi[(tt * 2 + kb) * 64 + lane];
            bf16x8 wlo = Wlo[(tt * 2 + kb) * 64 + lane];
            acc = __builtin_amdgcn_mfma_f32_16x16x32_bf16(wlo, xhi[kb], acc, 0, 0, 0);
            acc = __builtin_amdgcn_mfma_f32_16x16x32_bf16(whi, xlo[kb], acc, 0, 0, 0);
            acc = __builtin_amdgcn_mfma_f32_16x16x32_bf16(whi, xhi[kb], acc, 0, 0, 0);
        }
        if (node < n) {
            // lane holds o = 16*tt + 4*g + r, r=0..3 -> feature quad 4*tt+g
            ushort4 h;
            h.x = f2b_rn(acc[0] * dn);
            h.y = f2b_rn(acc[1] * dn);
            h.z = f2b_rn(acc[2] * dn);
            h.w = f2b_rn(acc[3] * dn);
            yh[(size_t)node * 16 + (tt * 4 + g)] = h;
        }
    }
}

// --- D3: per-bucket fused sort + gather of pre-scaled rows (r11 version) ---
__global__ __launch_bounds__(512, 4) void csr_gather_kernel(
    const unsigned int* __restrict__ grec, const int* __restrict__ gcur,
    const ushort4* __restrict__ yh, const float* __restrict__ bias,
    float4* __restrict__ out, int n) {
    __shared__ unsigned int sorted[CAP];  // 12288 B: src ids grouped by dst
    __shared__ int lh[BNODES];            // hist, then cursor
    __shared__ int ls[BNODES + 1];        // exclusive offsets; ls[128] = cnt
    __shared__ int wtot;
    int t = threadIdx.x;
    int b = blockIdx.x;
    size_t base = (size_t)b * CAP;
    int cnt = gcur[b];
    if (cnt > CAP) cnt = CAP;
    int node0 = b << BSHIFT;

    if (t < BNODES) lh[t] = 0;
    __syncthreads();
    for (int i = t; i < cnt; i += 512)
        atomicAdd(&lh[grec[base + i] & (BNODES - 1)], 1);
    __syncthreads();
    int c = 0, ex = 0;
    if (t < BNODES) {  // waves 0,1: inclusive shfl scan over 128 bins
        c = lh[t];
        int lane64 = t & 63;
        int v = c;
#pragma unroll
        for (int o = 1; o < 64; o <<= 1) {
            int u = __shfl_up(v, o, 64);
            if (lane64 >= o) v += u;
        }
        if (t == 63) wtot = v;
        ex = v - c;
    }
    __syncthreads();
    if (t >= 64 && t < BNODES) ex += wtot;
    if (t < BNODES) {
        ls[t] = ex;
        lh[t] = 0;  // cursor
        if (t == BNODES - 1) ls[BNODES] = ex + c;
    }
    __syncthreads();
    for (int i = t; i < cnt; i += 512) {  // re-read grec (L2-hot), sort into LDS
        unsigned int r = grec[base + i];
        int nd = r & (BNODES - 1);
        int pos = ls[nd] + atomicAdd(&lh[nd], 1);
        sorted[pos] = r >> BSHIFT;
    }
    __syncthreads();

    // ---- gather: wave w handles nodes [w*16, w*16+16) of this bucket ----
    int wave = t >> 6;
    int lane = t & 63;
    int grp = lane >> 4;   // which of 4 concurrent edges
    int fq = lane & 15;    // feature quad
    float4 bb = ((const float4*)bias)[fq];
    for (int i = 0; i < 16; ++i) {
        int nd = wave * 16 + i;
        int node = node0 + nd;
        if (node >= n) break;  // uniform per wave
        int beg = ls[nd];
        int end = ls[nd + 1];
        float dn = rsqrtf((float)(end - beg) + 1.0f);  // deg+1 (self loop)
        float4 acc = {0.f, 0.f, 0.f, 0.f};
        if (grp == 0) {  // self loop term y'_self (pre-scaled row)
            ushort4 h = yh[(size_t)node * 16 + fq];
            acc.x = b2f(h.x); acc.y = b2f(h.y);
            acc.z = b2f(h.z); acc.w = b2f(h.w);
        }
        int j = beg + grp;
        // 4x unrolled: four independent row loads in flight per iteration
        for (; j + 12 < end; j += 16) {
            int s0 = (int)sorted[j];
            int s1 = (int)sorted[j + 4];
            int s2 = (int)sorted[j + 8];
            int s3 = (int)sorted[j + 12];
            ushort4 h0 = yh[(size_t)s0 * 16 + fq];  // 128B rows
            ushort4 h1 = yh[(size_t)s1 * 16 + fq];
            ushort4 h2 = yh[(size_t)s2 * 16 + fq];
            ushort4 h3 = yh[(size_t)s3 * 16 + fq];
            acc.x += b2f(h0.x) + b2f(h1.x) + b2f(h2.x) + b2f(h3.x);
            acc.y += b2f(h0.y) + b2f(h1.y) + b2f(h2.y) + b2f(h3.y);
            acc.z += b2f(h0.z) + b2f(h1.z) + b2f(h2.z) + b2f(h3.z);
            acc.w += b2f(h0.w) + b2f(h1.w) + b2f(h2.w) + b2f(h3.w);
        }
        for (; j < end; j += 4) {  // tail, one per group-stride
            int s = (int)sorted[j];
            ushort4 h = yh[(size_t)s * 16 + fq];
            acc.x += b2f(h.x); acc.y += b2f(h.y);
            acc.z += b2f(h.z); acc.w += b2f(h.w);
        }
        for (int m = 16; m < 64; m <<= 1) {  // reduce 4 edge-groups
            acc.x += __shfl_xor(acc.x, m);
            acc.y += __shfl_xor(acc.y, m);
            acc.z += __shfl_xor(acc.z, m);
            acc.w += __shfl_xor(acc.w, m);
        }
        if (lane < 16) {
            float4 o;
            o.x = acc.x * dn + bb.x;
            o.y = acc.y * dn + bb.y;
            o.z = acc.z * dn + bb.z;
            o.w = acc.w * dn + bb.w;
            out[(size_t)node * 16 + lane] = o;
        }
    }
}

extern "C" void kernel_launch(void* const* d_in, const int* in_sizes, int n_in,
                              void* d_out, int out_size, void* d_ws, size_t ws_size,
                              hipStream_t stream) {
    const float* x    = (const float*)d_in[0];
    const int*   ei   = (const int*)d_in[1];  // [2,E]: src row then dst row
    const float* W    = (const float*)d_in[2];
    const float* bias = (const float*)d_in[3];
    float* out = (float*)d_out;

    int n = in_sizes[0] / 64;
    int e = in_sizes[1] / 2;
    int nbuck = (n + BNODES - 1) / BNODES;  // 782 (<=1024 for scatter scan)

    // workspace (256B aligned): gcur | grec | yh  (~23 MB)
    auto align = [](size_t v) { return (v + 255) & ~(size_t)255; };
    char* p = (char*)d_ws;
    int* gcur = (int*)p;                    p += align((size_t)nbuck * 4);
    unsigned int* grec = (unsigned int*)p;  p += align((size_t)nbuck * CAP * 4);
    ushort4* yh = (ushort4*)p;

    int sblocks = (e + EPB - 1) / EPB;   // 782

    hipMemsetAsync(gcur, 0, (size_t)nbuck * 4, stream);
    scatter_kernel<<<sblocks, 256, 0, stream>>>(ei, gcur, grec, e, nbuck);
    gemm_scaled_kernel<<<nbuck, 512, 0, stream>>>(x, W, yh, grec, gcur, n);
    csr_gather_kernel<<<nbuck, 512, 0, stream>>>(grec, gcur, yh, bias,
                                                 (float4*)out, n);
}

// Round 10
// 161.910 us; speedup vs baseline: 1.2734x; 1.2734x over previous
//
#include <hip/hip_runtime.h>

// GCN layer: out = (D^-1/2 (A+I) D^-1/2) X W^T + b
// N=100000, E=1600000, D=64.
//
// Round 21: eliminate the gcur atomic contention that floors the scatter.
// Evidence: r18(33KB LDS)=44us, r19(62KB)=44us, r20(25KB, 2x blocks)=75us
// -- occupancy/LDS/load-batching don't move it; block count does. Each
// block did ~725 RETURNING device-scope atomicAdds on 782 hot gcur words;
// queue depth ~ nblocks. Replace reservation with a deterministic
// counting sort (zero global atomics):
//   A hist:  391 blk x 4096 edges -> LDS hist -> h2[bucket][block]
//   B scan:  782 blk x 1 wave: exclusive scan h2[bb][:] -> off2d;
//            gcur[bb] = total (replaces memset + reservations)
//   C place: 391 blk: reload own h2 column (L2-hot, no re-hist), local
//            scan, LDS counting sort, write grec[bb*CAP + off2d + rank]
// gemm_scaled + csr_gather byte-identical to r18. Record order within a
// bucket changes (fp sum order) -- absmax stays at the bf16 quantum.
//
// Pipeline: D1 hist | D2 scan | D3 place | D4 gemm_scaled | D5 csr_gather

#define BSHIFT 7
#define BNODES 128
#define CAP 3072   // records per bucket region (mean 2046, P(overflow)~1e-90)
#define EPB 4096   // edges per scatter block -> 391 blocks
#define SPASS (EPB / 256)  // 16 unrolled iterations per pass

typedef short bf16x8 __attribute__((ext_vector_type(8)));
typedef float f32x4 __attribute__((ext_vector_type(4)));

__device__ inline unsigned short f2b_rn(float f) {
    unsigned u = __float_as_uint(f);
    unsigned r = u + 0x7FFFu + ((u >> 16) & 1u);
    return (unsigned short)(r >> 16);
}
__device__ inline float b2f(unsigned short h) {
    return __uint_as_float(((unsigned)h) << 16);
}

// split 8 fp32 (two float4) into hi (truncated bf16) + lo (bf16 of residual)
__device__ inline void split8(float4 a, float4 b, bf16x8* hi, bf16x8* lo) {
    float f[8] = {a.x, a.y, a.z, a.w, b.x, b.y, b.z, b.w};
    union U { unsigned u[4]; bf16x8 v; } uh, ul;
#pragma unroll
    for (int i = 0; i < 4; ++i) {
        unsigned u0 = __float_as_uint(f[2 * i]);
        unsigned u1 = __float_as_uint(f[2 * i + 1]);
        uh.u[i] = (u0 >> 16) | (u1 & 0xFFFF0000u);
        float r0 = f[2 * i]     - __uint_as_float(u0 & 0xFFFF0000u);
        float r1 = f[2 * i + 1] - __uint_as_float(u1 & 0xFFFF0000u);
        unsigned v0 = __float_as_uint(r0);
        unsigned v1 = __float_as_uint(r1);
        ul.u[i] = (v0 >> 16) | (v1 & 0xFFFF0000u);
    }
    *hi = uh.v;
    *lo = ul.v;
}

// --- D1: per-block bucket histogram -> h2[bucket][block] ---
__global__ __launch_bounds__(256) void hist_kernel(
    const int* __restrict__ ei, int* __restrict__ h2,
    int e, int G, int nbuck) {
    __shared__ int lh[1024];
    int t = threadIdx.x;
    int g = blockIdx.x;
    for (int i = t; i < nbuck; i += 256) lh[i] = 0;
    __syncthreads();
    int e0 = g * EPB;
    int m = e - e0;
    if (m > EPB) m = EPB;
#pragma unroll
    for (int j = 0; j < SPASS; ++j) {
        int i = t + j * 256;
        if (i < m) atomicAdd(&lh[ei[e + e0 + i] >> BSHIFT], 1);
    }
    __syncthreads();
    for (int bb = t; bb < nbuck; bb += 256)
        h2[(size_t)bb * G + g] = lh[bb];
}

// --- D2: per-bucket exclusive scan over blocks; gcur[bb] = total ---
__global__ __launch_bounds__(64) void scan_kernel(
    const int* __restrict__ h2, int* __restrict__ off2d,
    int* __restrict__ gcur, int G) {
    int bb = blockIdx.x;
    int lane = threadIdx.x;
    int carry = 0;
    int nch = (G + 63) >> 6;
    for (int c = 0; c < nch; ++c) {
        int idx = c * 64 + lane;
        int v = (idx < G) ? h2[(size_t)bb * G + idx] : 0;
        int vi = v;
#pragma unroll
        for (int o = 1; o < 64; o <<= 1) {
            int u = __shfl_up(vi, o, 64);
            if (lane >= o) vi += u;
        }
        if (idx < G) off2d[(size_t)bb * G + idx] = carry + vi - v;
        carry += __shfl(vi, 63, 64);
    }
    if (lane == 0) gcur[bb] = carry;
}

// --- D3: deterministic place -- LDS counting sort, zero global atomics ---
__global__ __launch_bounds__(256) void place_kernel(
    const int* __restrict__ ei, const int* __restrict__ h2,
    const int* __restrict__ off2d, unsigned int* __restrict__ grec,
    int e, int G, int nbuck) {
    __shared__ unsigned int lsort[EPB];      // 16384 B: records sorted by bucket
    __shared__ unsigned short sbk[EPB];      //  8192 B: bucket of sorted slot
    __shared__ int lh[1024];                 //  4096 B: cursor
    __shared__ int lscan[1024];              //  4096 B: local exclusive offsets
    __shared__ int goff[1024];               //  4096 B: off2d for this column
    __shared__ int wsum[4];
    int t = threadIdx.x;
    int g = blockIdx.x;

    // load own hist column (L2-hot; written by hist_kernel)
    for (int bb = t; bb < nbuck; bb += 256) {
        lh[bb] = h2[(size_t)bb * G + g];
        goff[bb] = off2d[(size_t)bb * G + g];
    }
    __syncthreads();

    // local exclusive scan over nbuck bins (4 bins/thread + shfl scan)
    int b0 = t << 2;
    int c[4], v4[4], ssum = 0;
#pragma unroll
    for (int j = 0; j < 4; ++j) {
        int bb = b0 + j;
        int v = (bb < nbuck) ? lh[bb] : 0;
        c[j] = ssum;
        v4[j] = v;
        ssum += v;
    }
    int lane = t & 63, w = t >> 6;
    int vi = ssum;
#pragma unroll
    for (int o = 1; o < 64; o <<= 1) {
        int u = __shfl_up(vi, o, 64);
        if (lane >= o) vi += u;
    }
    if (lane == 63) wsum[w] = vi;
    __syncthreads();
    int woff = 0;
#pragma unroll
    for (int j = 0; j < 4; ++j)
        if (j < w) woff += wsum[j];
    int ex = woff + vi - ssum;
#pragma unroll
    for (int j = 0; j < 4; ++j) {
        int bb = b0 + j;
        if (bb < nbuck) {
            lscan[bb] = ex + c[j];
            lh[bb] = 0;  // cursor for sort pass
        }
    }
    __syncthreads();

    int e0 = g * EPB;
    int m = e - e0;
    if (m > EPB) m = EPB;

    // LDS counting sort (re-read ei; L2/L3-hot second read)
#pragma unroll
    for (int j = 0; j < SPASS; ++j) {
        int i = t + j * 256;
        if (i < m) {
            int gg = e0 + i;
            int s = ei[gg];
            int d = ei[e + gg];
            int b = d >> BSHIFT;
            int sp = lscan[b] + atomicAdd(&lh[b], 1);
            lsort[sp] = ((unsigned int)s << BSHIFT) | (unsigned int)(d & (BNODES - 1));
            sbk[sp] = (unsigned short)b;
        }
    }
    __syncthreads();

    // deterministic coalesced write
#pragma unroll
    for (int j = 0; j < SPASS; ++j) {
        int i = t + j * 256;
        if (i < m) {
            int b = sbk[i];
            int posb = goff[b] + (i - lscan[b]);
            if (posb < CAP)
                grec[(size_t)b * CAP + posb] = lsort[i];
        }
    }
}

// --- D4: bucket-aligned MFMA gemm + deg hist + pre-scaled bf16 out ---
// Block b = bucket b = nodes [128b, 128b+128); 512 thr = 8 waves x 16 nodes.
__global__ __launch_bounds__(512) void gemm_scaled_kernel(
    const float* __restrict__ x, const float* __restrict__ W,
    ushort4* __restrict__ yh,
    const unsigned int* __restrict__ grec, const int* __restrict__ gcur,
    int n) {
    __shared__ bf16x8 Whi[512];   // 8KB: pre-split W fragments, frag f =
    __shared__ bf16x8 Wlo[512];   // 8KB: ((tt*2+kb)*4+g)*16+jn  (= lane order)
    __shared__ int lh[BNODES];
    int t = threadIdx.x;
    int b = blockIdx.x;
    int node0 = b << BSHIFT;

    if (t < BNODES) lh[t] = 0;
    __syncthreads();

    // deg hist over this bucket's grec region (~2K records, L2/L3-hot)
    size_t base = (size_t)b * CAP;
    int cnt = gcur[b];
    if (cnt > CAP) cnt = CAP;
    for (int i = t; i < cnt; i += 512)
        atomicAdd(&lh[grec[base + i] & (BNODES - 1)], 1);

    // stage split-bf16 W fragments (once per block; 16KB L2-hot reads)
    {
        int tt = t >> 7, kb = (t >> 6) & 1, g = (t >> 4) & 3, jn = t & 15;
        const float4* wp =
            (const float4*)(W + (size_t)(tt * 16 + jn) * 64 + kb * 32 + g * 8);
        bf16x8 hi, lo;
        split8(wp[0], wp[1], &hi, &lo);
        Whi[t] = hi;
        Wlo[t] = lo;
    }
    __syncthreads();

    int wave = t >> 6, lane = t & 63;
    int jn = lane & 15;      // node within wave tile (B-frag / D col)
    int g = lane >> 4;       // k-subgroup: elements k = 8g..8g+7 (+32*kb)
    int node = node0 + wave * 16 + jn;

    // x fragments: hi/lo for kb=0,1
    bf16x8 xhi[2], xlo[2];
#pragma unroll
    for (int kb = 0; kb < 2; ++kb) {
        float4 p0 = {0.f, 0.f, 0.f, 0.f}, p1 = {0.f, 0.f, 0.f, 0.f};
        if (node < n) {
            const float4* xp =
                (const float4*)(x + (size_t)node * 64 + kb * 32 + g * 8);
            p0 = xp[0];
            p1 = xp[1];
        }
        split8(p0, p1, &xhi[kb], &xlo[kb]);
    }

    float dn = rsqrtf((float)lh[wave * 16 + jn] + 1.0f);  // +1 self loop

#pragma unroll
    for (int tt = 0; tt < 4; ++tt) {
        f32x4 acc = {0.f, 0.f, 0.f, 0.f};
#pragma unroll
        for (int kb = 0; kb < 2; ++kb) {
            bf16x8 whi = Whi[(tt * 2 + kb) * 64 + lane];
            bf16x8 wlo = Wlo[(tt * 2 + kb) * 64 + lane];
            acc = __builtin_amdgcn_mfma_f32_16x16x32_bf16(wlo, xhi[kb], acc, 0, 0, 0);
            acc = __builtin_amdgcn_mfma_f32_16x16x32_bf16(whi, xlo[kb], acc, 0, 0, 0);
            acc = __builtin_amdgcn_mfma_f32_16x16x32_bf16(whi, xhi[kb], acc, 0, 0, 0);
        }
        if (node < n) {
            // lane holds o = 16*tt + 4*g + r, r=0..3 -> feature quad 4*tt+g
            ushort4 h;
            h.x = f2b_rn(acc[0] * dn);
            h.y = f2b_rn(acc[1] * dn);
            h.z = f2b_rn(acc[2] * dn);
            h.w = f2b_rn(acc[3] * dn);
            yh[(size_t)node * 16 + (tt * 4 + g)] = h;
        }
    }
}

// --- D5: per-bucket fused sort + gather of pre-scaled rows (r11 version) ---
__global__ __launch_bounds__(512, 4) void csr_gather_kernel(
    const unsigned int* __restrict__ grec, const int* __restrict__ gcur,
    const ushort4* __restrict__ yh, const float* __restrict__ bias,
    float4* __restrict__ out, int n) {
    __shared__ unsigned int sorted[CAP];  // 12288 B: src ids grouped by dst
    __shared__ int lh[BNODES];            // hist, then cursor
    __shared__ int ls[BNODES + 1];        // exclusive offsets; ls[128] = cnt
    __shared__ int wtot;
    int t = threadIdx.x;
    int b = blockIdx.x;
    size_t base = (size_t)b * CAP;
    int cnt = gcur[b];
    if (cnt > CAP) cnt = CAP;
    int node0 = b << BSHIFT;

    if (t < BNODES) lh[t] = 0;
    __syncthreads();
    for (int i = t; i < cnt; i += 512)
        atomicAdd(&lh[grec[base + i] & (BNODES - 1)], 1);
    __syncthreads();
    int c = 0, ex = 0;
    if (t < BNODES) {  // waves 0,1: inclusive shfl scan over 128 bins
        c = lh[t];
        int lane64 = t & 63;
        int v = c;
#pragma unroll
        for (int o = 1; o < 64; o <<= 1) {
            int u = __shfl_up(v, o, 64);
            if (lane64 >= o) v += u;
        }
        if (t == 63) wtot = v;
        ex = v - c;
    }
    __syncthreads();
    if (t >= 64 && t < BNODES) ex += wtot;
    if (t < BNODES) {
        ls[t] = ex;
        lh[t] = 0;  // cursor
        if (t == BNODES - 1) ls[BNODES] = ex + c;
    }
    __syncthreads();
    for (int i = t; i < cnt; i += 512) {  // re-read grec (L2-hot), sort into LDS
        unsigned int r = grec[base + i];
        int nd = r & (BNODES - 1);
        int pos = ls[nd] + atomicAdd(&lh[nd], 1);
        sorted[pos] = r >> BSHIFT;
    }
    __syncthreads();

    // ---- gather: wave w handles nodes [w*16, w*16+16) of this bucket ----
    int wave = t >> 6;
    int lane = t & 63;
    int grp = lane >> 4;   // which of 4 concurrent edges
    int fq = lane & 15;    // feature quad
    float4 bb = ((const float4*)bias)[fq];
    for (int i = 0; i < 16; ++i) {
        int nd = wave * 16 + i;
        int node = node0 + nd;
        if (node >= n) break;  // uniform per wave
        int beg = ls[nd];
        int end = ls[nd + 1];
        float dn = rsqrtf((float)(end - beg) + 1.0f);  // deg+1 (self loop)
        float4 acc = {0.f, 0.f, 0.f, 0.f};
        if (grp == 0) {  // self loop term y'_self (pre-scaled row)
            ushort4 h = yh[(size_t)node * 16 + fq];
            acc.x = b2f(h.x); acc.y = b2f(h.y);
            acc.z = b2f(h.z); acc.w = b2f(h.w);
        }
        int j = beg + grp;
        // 4x unrolled: four independent row loads in flight per iteration
        for (; j + 12 < end; j += 16) {
            int s0 = (int)sorted[j];
            int s1 = (int)sorted[j + 4];
            int s2 = (int)sorted[j + 8];
            int s3 = (int)sorted[j + 12];
            ushort4 h0 = yh[(size_t)s0 * 16 + fq];  // 128B rows
            ushort4 h1 = yh[(size_t)s1 * 16 + fq];
            ushort4 h2 = yh[(size_t)s2 * 16 + fq];
            ushort4 h3 = yh[(size_t)s3 * 16 + fq];
            acc.x += b2f(h0.x) + b2f(h1.x) + b2f(h2.x) + b2f(h3.x);
            acc.y += b2f(h0.y) + b2f(h1.y) + b2f(h2.y) + b2f(h3.y);
            acc.z += b2f(h0.z) + b2f(h1.z) + b2f(h2.z) + b2f(h3.z);
            acc.w += b2f(h0.w) + b2f(h1.w) + b2f(h2.w) + b2f(h3.w);
        }
        for (; j < end; j += 4) {  // tail, one per group-stride
            int s = (int)sorted[j];
            ushort4 h = yh[(size_t)s * 16 + fq];
            acc.x += b2f(h.x); acc.y += b2f(h.y);
            acc.z += b2f(h.z); acc.w += b2f(h.w);
        }
        for (int m = 16; m < 64; m <<= 1) {  // reduce 4 edge-groups
            acc.x += __shfl_xor(acc.x, m);
            acc.y += __shfl_xor(acc.y, m);
            acc.z += __shfl_xor(acc.z, m);
            acc.w += __shfl_xor(acc.w, m);
        }
        if (lane < 16) {
            float4 o;
            o.x = acc.x * dn + bb.x;
            o.y = acc.y * dn + bb.y;
            o.z = acc.z * dn + bb.z;
            o.w = acc.w * dn + bb.w;
            out[(size_t)node * 16 + lane] = o;
        }
    }
}

extern "C" void kernel_launch(void* const* d_in, const int* in_sizes, int n_in,
                              void* d_out, int out_size, void* d_ws, size_t ws_size,
                              hipStream_t stream) {
    const float* x    = (const float*)d_in[0];
    const int*   ei   = (const int*)d_in[1];  // [2,E]: src row then dst row
    const float* W    = (const float*)d_in[2];
    const float* bias = (const float*)d_in[3];
    float* out = (float*)d_out;

    int n = in_sizes[0] / 64;
    int e = in_sizes[1] / 2;
    int nbuck = (n + BNODES - 1) / BNODES;  // 782 (<=1024 for scans)
    int G = (e + EPB - 1) / EPB;            // 391 scatter blocks

    // workspace (256B aligned): gcur | h2 | off2d | grec | yh  (~26 MB)
    auto align = [](size_t v) { return (v + 255) & ~(size_t)255; };
    char* p = (char*)d_ws;
    int* gcur = (int*)p;                    p += align((size_t)nbuck * 4);
    int* h2 = (int*)p;                      p += align((size_t)nbuck * G * 4);
    int* off2d = (int*)p;                   p += align((size_t)nbuck * G * 4);
    unsigned int* grec = (unsigned int*)p;  p += align((size_t)nbuck * CAP * 4);
    ushort4* yh = (ushort4*)p;

    hist_kernel<<<G, 256, 0, stream>>>(ei, h2, e, G, nbuck);
    scan_kernel<<<nbuck, 64, 0, stream>>>(h2, off2d, gcur, G);
    place_kernel<<<G, 256, 0, stream>>>(ei, h2, off2d, grec, e, G, nbuck);
    gemm_scaled_kernel<<<nbuck, 512, 0, stream>>>(x, W, yh, grec, gcur, n);
    csr_gather_kernel<<<nbuck, 512, 0, stream>>>(grec, gcur, yh, bias,
                                                 (float4*)out, n);
}

// Round 11
// 155.017 us; speedup vs baseline: 1.3301x; 1.0445x over previous
//
#include <hip/hip_runtime.h>

// GCN layer: out = (D^-1/2 (A+I) D^-1/2) X W^T + b
// N=100000, E=1600000, D=64.
//
// Round 22: fix the transposed-matrix coalescing in the counting-sort
// pipeline. r21 accounting left 72.5us for hist+scan+place+gemm+gaps
// (arithmetic says ~35): culprit is the h2/off2d [bucket][block] layout:
//   - hist block g wrote h2[bb*G+g] -> 782 scattered 32B sectors/block
//     (~10MB write-through, r12 failure mode in miniature)
//   - place block g read h2/off2d at stride 1564B -> 2x782 uncoalesced
//     4B loads pulling 64B lines each (~39MB effective + serial latency)
// Transpose to [g][bb]: hist writes and place reads become contiguous;
// scan reads become strided-but-parallel (782 independent 1-wave blocks,
// latency-hidden; writes fire-and-forget). Also widen hist/place to 512
// threads (8-deep guarded passes; place bin-scan = 2 bins/thread, 8
// waves). gemm_scaled + csr_gather byte-identical to r21; identical
// record placement -> bit-identical output.
//
// Pipeline: D1 hist | D2 scan | D3 place | D4 gemm_scaled | D5 csr_gather

#define BSHIFT 7
#define BNODES 128
#define CAP 3072   // records per bucket region (mean 2046, P(overflow)~1e-90)
#define EPB 4096   // edges per scatter block -> 391 blocks

typedef short bf16x8 __attribute__((ext_vector_type(8)));
typedef float f32x4 __attribute__((ext_vector_type(4)));

__device__ inline unsigned short f2b_rn(float f) {
    unsigned u = __float_as_uint(f);
    unsigned r = u + 0x7FFFu + ((u >> 16) & 1u);
    return (unsigned short)(r >> 16);
}
__device__ inline float b2f(unsigned short h) {
    return __uint_as_float(((unsigned)h) << 16);
}

// split 8 fp32 (two float4) into hi (truncated bf16) + lo (bf16 of residual)
__device__ inline void split8(float4 a, float4 b, bf16x8* hi, bf16x8* lo) {
    float f[8] = {a.x, a.y, a.z, a.w, b.x, b.y, b.z, b.w};
    union U { unsigned u[4]; bf16x8 v; } uh, ul;
#pragma unroll
    for (int i = 0; i < 4; ++i) {
        unsigned u0 = __float_as_uint(f[2 * i]);
        unsigned u1 = __float_as_uint(f[2 * i + 1]);
        uh.u[i] = (u0 >> 16) | (u1 & 0xFFFF0000u);
        float r0 = f[2 * i]     - __uint_as_float(u0 & 0xFFFF0000u);
        float r1 = f[2 * i + 1] - __uint_as_float(u1 & 0xFFFF0000u);
        unsigned v0 = __float_as_uint(r0);
        unsigned v1 = __float_as_uint(r1);
        ul.u[i] = (v0 >> 16) | (v1 & 0xFFFF0000u);
    }
    *hi = uh.v;
    *lo = ul.v;
}

// --- D1: per-block bucket histogram -> h2[g][bb] (coalesced write) ---
__global__ __launch_bounds__(512) void hist_kernel(
    const int* __restrict__ ei, int* __restrict__ h2,
    int e, int G, int nbuck) {
    __shared__ int lh[1024];
    int t = threadIdx.x;
    int g = blockIdx.x;
    for (int i = t; i < nbuck; i += 512) lh[i] = 0;
    __syncthreads();
    int e0 = g * EPB;
    int m = e - e0;
    if (m > EPB) m = EPB;
#pragma unroll
    for (int j = 0; j < 8; ++j) {
        int i = t + j * 512;
        if (i < m) atomicAdd(&lh[ei[e + e0 + i] >> BSHIFT], 1);
    }
    __syncthreads();
    for (int bb = t; bb < nbuck; bb += 512)
        h2[(size_t)g * nbuck + bb] = lh[bb];
}

// --- D2: per-bucket exclusive scan over blocks; gcur[bb] = total ---
// reads h2[g][bb] (strided, latency-hidden across 782 blocks); writes
// off2d[g][bb] fire-and-forget.
__global__ __launch_bounds__(64) void scan_kernel(
    const int* __restrict__ h2, int* __restrict__ off2d,
    int* __restrict__ gcur, int G, int nbuck) {
    int bb = blockIdx.x;
    int lane = threadIdx.x;
    int carry = 0;
    int nch = (G + 63) >> 6;
    for (int c = 0; c < nch; ++c) {
        int idx = c * 64 + lane;
        int v = (idx < G) ? h2[(size_t)idx * nbuck + bb] : 0;
        int vi = v;
#pragma unroll
        for (int o = 1; o < 64; o <<= 1) {
            int u = __shfl_up(vi, o, 64);
            if (lane >= o) vi += u;
        }
        if (idx < G) off2d[(size_t)idx * nbuck + bb] = carry + vi - v;
        carry += __shfl(vi, 63, 64);
    }
    if (lane == 0) gcur[bb] = carry;
}

// --- D3: deterministic place -- coalesced h2/off2d reads, 512 threads ---
__global__ __launch_bounds__(512) void place_kernel(
    const int* __restrict__ ei, const int* __restrict__ h2,
    const int* __restrict__ off2d, unsigned int* __restrict__ grec,
    int e, int G, int nbuck) {
    __shared__ unsigned int lsort[EPB];      // 16384 B: records sorted by bucket
    __shared__ unsigned short sbk[EPB];      //  8192 B: bucket of sorted slot
    __shared__ int lh[1024];                 //  4096 B: counts, then cursor
    __shared__ int lscan[1024];              //  4096 B: local exclusive offsets
    __shared__ int goff[1024];               //  4096 B: off2d for this column
    __shared__ int wsum[8];
    int t = threadIdx.x;
    int g = blockIdx.x;

    // load own hist row + global offsets (contiguous -> coalesced)
    for (int bb = t; bb < nbuck; bb += 512) {
        lh[bb] = h2[(size_t)g * nbuck + bb];
        goff[bb] = off2d[(size_t)g * nbuck + bb];
    }
    __syncthreads();

    // local exclusive scan over nbuck bins (2 bins/thread, 8-wave scan)
    int b0 = t << 1;
    int v0a = (b0 < nbuck) ? lh[b0] : 0;
    int v1a = (b0 + 1 < nbuck) ? lh[b0 + 1] : 0;
    int ssum = v0a + v1a;
    int lane = t & 63, w = t >> 6;
    int vi = ssum;
#pragma unroll
    for (int o = 1; o < 64; o <<= 1) {
        int u = __shfl_up(vi, o, 64);
        if (lane >= o) vi += u;
    }
    if (lane == 63) wsum[w] = vi;
    __syncthreads();
    int woff = 0;
#pragma unroll
    for (int j = 0; j < 8; ++j)
        if (j < w) woff += wsum[j];
    int ex = woff + vi - ssum;
    if (b0 < nbuck) { lscan[b0] = ex; lh[b0] = 0; }
    if (b0 + 1 < nbuck) { lscan[b0 + 1] = ex + v0a; lh[b0 + 1] = 0; }
    __syncthreads();

    int e0 = g * EPB;
    int m = e - e0;
    if (m > EPB) m = EPB;

    // LDS counting sort (re-read ei; dst row L2-hot)
#pragma unroll
    for (int j = 0; j < 8; ++j) {
        int i = t + j * 512;
        if (i < m) {
            int gg = e0 + i;
            int s = ei[gg];
            int d = ei[e + gg];
            int b = d >> BSHIFT;
            int sp = lscan[b] + atomicAdd(&lh[b], 1);
            lsort[sp] = ((unsigned int)s << BSHIFT) | (unsigned int)(d & (BNODES - 1));
            sbk[sp] = (unsigned short)b;
        }
    }
    __syncthreads();

    // deterministic coalesced write
#pragma unroll
    for (int j = 0; j < 8; ++j) {
        int i = t + j * 512;
        if (i < m) {
            int b = sbk[i];
            int posb = goff[b] + (i - lscan[b]);
            if (posb < CAP)
                grec[(size_t)b * CAP + posb] = lsort[i];
        }
    }
}

// --- D4: bucket-aligned MFMA gemm + deg hist + pre-scaled bf16 out ---
// Block b = bucket b = nodes [128b, 128b+128); 512 thr = 8 waves x 16 nodes.
__global__ __launch_bounds__(512) void gemm_scaled_kernel(
    const float* __restrict__ x, const float* __restrict__ W,
    ushort4* __restrict__ yh,
    const unsigned int* __restrict__ grec, const int* __restrict__ gcur,
    int n) {
    __shared__ bf16x8 Whi[512];   // 8KB: pre-split W fragments, frag f =
    __shared__ bf16x8 Wlo[512];   // 8KB: ((tt*2+kb)*4+g)*16+jn  (= lane order)
    __shared__ int lh[BNODES];
    int t = threadIdx.x;
    int b = blockIdx.x;
    int node0 = b << BSHIFT;

    if (t < BNODES) lh[t] = 0;
    __syncthreads();

    // deg hist over this bucket's grec region (~2K records, L2/L3-hot)
    size_t base = (size_t)b * CAP;
    int cnt = gcur[b];
    if (cnt > CAP) cnt = CAP;
    for (int i = t; i < cnt; i += 512)
        atomicAdd(&lh[grec[base + i] & (BNODES - 1)], 1);

    // stage split-bf16 W fragments (once per block; 16KB L2-hot reads)
    {
        int tt = t >> 7, kb = (t >> 6) & 1, g = (t >> 4) & 3, jn = t & 15;
        const float4* wp =
            (const float4*)(W + (size_t)(tt * 16 + jn) * 64 + kb * 32 + g * 8);
        bf16x8 hi, lo;
        split8(wp[0], wp[1], &hi, &lo);
        Whi[t] = hi;
        Wlo[t] = lo;
    }
    __syncthreads();

    int wave = t >> 6, lane = t & 63;
    int jn = lane & 15;      // node within wave tile (B-frag / D col)
    int g = lane >> 4;       // k-subgroup: elements k = 8g..8g+7 (+32*kb)
    int node = node0 + wave * 16 + jn;

    // x fragments: hi/lo for kb=0,1
    bf16x8 xhi[2], xlo[2];
#pragma unroll
    for (int kb = 0; kb < 2; ++kb) {
        float4 p0 = {0.f, 0.f, 0.f, 0.f}, p1 = {0.f, 0.f, 0.f, 0.f};
        if (node < n) {
            const float4* xp =
                (const float4*)(x + (size_t)node * 64 + kb * 32 + g * 8);
            p0 = xp[0];
            p1 = xp[1];
        }
        split8(p0, p1, &xhi[kb], &xlo[kb]);
    }

    float dn = rsqrtf((float)lh[wave * 16 + jn] + 1.0f);  // +1 self loop

#pragma unroll
    for (int tt = 0; tt < 4; ++tt) {
        f32x4 acc = {0.f, 0.f, 0.f, 0.f};
#pragma unroll
        for (int kb = 0; kb < 2; ++kb) {
            bf16x8 whi = Whi[(tt * 2 + kb) * 64 + lane];
            bf16x8 wlo = Wlo[(tt * 2 + kb) * 64 + lane];
            acc = __builtin_amdgcn_mfma_f32_16x16x32_bf16(wlo, xhi[kb], acc, 0, 0, 0);
            acc = __builtin_amdgcn_mfma_f32_16x16x32_bf16(whi, xlo[kb], acc, 0, 0, 0);
            acc = __builtin_amdgcn_mfma_f32_16x16x32_bf16(whi, xhi[kb], acc, 0, 0, 0);
        }
        if (node < n) {
            // lane holds o = 16*tt + 4*g + r, r=0..3 -> feature quad 4*tt+g
            ushort4 h;
            h.x = f2b_rn(acc[0] * dn);
            h.y = f2b_rn(acc[1] * dn);
            h.z = f2b_rn(acc[2] * dn);
            h.w = f2b_rn(acc[3] * dn);
            yh[(size_t)node * 16 + (tt * 4 + g)] = h;
        }
    }
}

// --- D5: per-bucket fused sort + gather of pre-scaled rows (r11 version) ---
__global__ __launch_bounds__(512, 4) void csr_gather_kernel(
    const unsigned int* __restrict__ grec, const int* __restrict__ gcur,
    const ushort4* __restrict__ yh, const float* __restrict__ bias,
    float4* __restrict__ out, int n) {
    __shared__ unsigned int sorted[CAP];  // 12288 B: src ids grouped by dst
    __shared__ int lh[BNODES];            // hist, then cursor
    __shared__ int ls[BNODES + 1];        // exclusive offsets; ls[128] = cnt
    __shared__ int wtot;
    int t = threadIdx.x;
    int b = blockIdx.x;
    size_t base = (size_t)b * CAP;
    int cnt = gcur[b];
    if (cnt > CAP) cnt = CAP;
    int node0 = b << BSHIFT;

    if (t < BNODES) lh[t] = 0;
    __syncthreads();
    for (int i = t; i < cnt; i += 512)
        atomicAdd(&lh[grec[base + i] & (BNODES - 1)], 1);
    __syncthreads();
    int c = 0, ex = 0;
    if (t < BNODES) {  // waves 0,1: inclusive shfl scan over 128 bins
        c = lh[t];
        int lane64 = t & 63;
        int v = c;
#pragma unroll
        for (int o = 1; o < 64; o <<= 1) {
            int u = __shfl_up(v, o, 64);
            if (lane64 >= o) v += u;
        }
        if (t == 63) wtot = v;
        ex = v - c;
    }
    __syncthreads();
    if (t >= 64 && t < BNODES) ex += wtot;
    if (t < BNODES) {
        ls[t] = ex;
        lh[t] = 0;  // cursor
        if (t == BNODES - 1) ls[BNODES] = ex + c;
    }
    __syncthreads();
    for (int i = t; i < cnt; i += 512) {  // re-read grec (L2-hot), sort into LDS
        unsigned int r = grec[base + i];
        int nd = r & (BNODES - 1);
        int pos = ls[nd] + atomicAdd(&lh[nd], 1);
        sorted[pos] = r >> BSHIFT;
    }
    __syncthreads();

    // ---- gather: wave w handles nodes [w*16, w*16+16) of this bucket ----
    int wave = t >> 6;
    int lane = t & 63;
    int grp = lane >> 4;   // which of 4 concurrent edges
    int fq = lane & 15;    // feature quad
    float4 bb = ((const float4*)bias)[fq];
    for (int i = 0; i < 16; ++i) {
        int nd = wave * 16 + i;
        int node = node0 + nd;
        if (node >= n) break;  // uniform per wave
        int beg = ls[nd];
        int end = ls[nd + 1];
        float dn = rsqrtf((float)(end - beg) + 1.0f);  // deg+1 (self loop)
        float4 acc = {0.f, 0.f, 0.f, 0.f};
        if (grp == 0) {  // self loop term y'_self (pre-scaled row)
            ushort4 h = yh[(size_t)node * 16 + fq];
            acc.x = b2f(h.x); acc.y = b2f(h.y);
            acc.z = b2f(h.z); acc.w = b2f(h.w);
        }
        int j = beg + grp;
        // 4x unrolled: four independent row loads in flight per iteration
        for (; j + 12 < end; j += 16) {
            int s0 = (int)sorted[j];
            int s1 = (int)sorted[j + 4];
            int s2 = (int)sorted[j + 8];
            int s3 = (int)sorted[j + 12];
            ushort4 h0 = yh[(size_t)s0 * 16 + fq];  // 128B rows
            ushort4 h1 = yh[(size_t)s1 * 16 + fq];
            ushort4 h2 = yh[(size_t)s2 * 16 + fq];
            ushort4 h3 = yh[(size_t)s3 * 16 + fq];
            acc.x += b2f(h0.x) + b2f(h1.x) + b2f(h2.x) + b2f(h3.x);
            acc.y += b2f(h0.y) + b2f(h1.y) + b2f(h2.y) + b2f(h3.y);
            acc.z += b2f(h0.z) + b2f(h1.z) + b2f(h2.z) + b2f(h3.z);
            acc.w += b2f(h0.w) + b2f(h1.w) + b2f(h2.w) + b2f(h3.w);
        }
        for (; j < end; j += 4) {  // tail, one per group-stride
            int s = (int)sorted[j];
            ushort4 h = yh[(size_t)s * 16 + fq];
            acc.x += b2f(h.x); acc.y += b2f(h.y);
            acc.z += b2f(h.z); acc.w += b2f(h.w);
        }
        for (int m = 16; m < 64; m <<= 1) {  // reduce 4 edge-groups
            acc.x += __shfl_xor(acc.x, m);
            acc.y += __shfl_xor(acc.y, m);
            acc.z += __shfl_xor(acc.z, m);
            acc.w += __shfl_xor(acc.w, m);
        }
        if (lane < 16) {
            float4 o;
            o.x = acc.x * dn + bb.x;
            o.y = acc.y * dn + bb.y;
            o.z = acc.z * dn + bb.z;
            o.w = acc.w * dn + bb.w;
            out[(size_t)node * 16 + lane] = o;
        }
    }
}

extern "C" void kernel_launch(void* const* d_in, const int* in_sizes, int n_in,
                              void* d_out, int out_size, void* d_ws, size_t ws_size,
                              hipStream_t stream) {
    const float* x    = (const float*)d_in[0];
    const int*   ei   = (const int*)d_in[1];  // [2,E]: src row then dst row
    const float* W    = (const float*)d_in[2];
    const float* bias = (const float*)d_in[3];
    float* out = (float*)d_out;

    int n = in_sizes[0] / 64;
    int e = in_sizes[1] / 2;
    int nbuck = (n + BNODES - 1) / BNODES;  // 782 (<=1024 for scans)
    int G = (e + EPB - 1) / EPB;            // 391 scatter blocks

    // workspace (256B aligned): gcur | h2 | off2d | grec | yh  (~26 MB)
    auto align = [](size_t v) { return (v + 255) & ~(size_t)255; };
    char* p = (char*)d_ws;
    int* gcur = (int*)p;                    p += align((size_t)nbuck * 4);
    int* h2 = (int*)p;                      p += align((size_t)G * nbuck * 4);
    int* off2d = (int*)p;                   p += align((size_t)G * nbuck * 4);
    unsigned int* grec = (unsigned int*)p;  p += align((size_t)nbuck * CAP * 4);
    ushort4* yh = (ushort4*)p;

    hist_kernel<<<G, 512, 0, stream>>>(ei, h2, e, G, nbuck);
    scan_kernel<<<nbuck, 64, 0, stream>>>(h2, off2d, gcur, G, nbuck);
    place_kernel<<<G, 512, 0, stream>>>(ei, h2, off2d, grec, e, G, nbuck);
    gemm_scaled_kernel<<<nbuck, 512, 0, stream>>>(x, W, yh, grec, gcur, n);
    csr_gather_kernel<<<nbuck, 512, 0, stream>>>(grec, gcur, yh, bias,
                                                 (float4*)out, n);
}